// Round 13
// baseline (149.522 us; speedup 1.0000x reference)
//
#include <hip/hip_runtime.h>

typedef unsigned short u16;
typedef unsigned int u32;
typedef __attribute__((ext_vector_type(4))) unsigned short u16x4;
typedef __attribute__((ext_vector_type(8))) short short8;
typedef __attribute__((ext_vector_type(4))) float f32x4;
typedef __attribute__((ext_vector_type(8))) float f32x8;
typedef __attribute__((ext_vector_type(2))) unsigned int u32x2;

#define MFMA(a, b, c) __builtin_amdgcn_mfma_f32_16x16x32_bf16((a), (b), (c), 0, 0, 0)

__device__ __forceinline__ u16 f2bf(float f) {
    union { float f; unsigned int u; } v; v.f = f;
    unsigned int u = v.u;
    return (u16)((u + 0x7fffu + ((u >> 16) & 1u)) >> 16);
}

__device__ __forceinline__ float exp2fast(float x) {
#if __has_builtin(__builtin_amdgcn_exp2f)
    return __builtin_amdgcn_exp2f(x);
#else
    return exp2f(x);
#endif
}

__device__ __forceinline__ unsigned int cvtpk(float lo, float hi) {
    unsigned int r;
    asm("v_cvt_pk_bf16_f32 %0, %1, %2" : "=v"(r) : "v"(lo), "v"(hi));
    return r;
}

// async global->LDS, 16B per lane; LDS dest = wave-uniform base + lane*16
__device__ __forceinline__ void gload16(const void* g, void* l) {
    __builtin_amdgcn_global_load_lds((const __attribute__((address_space(1))) unsigned int*)g,
                                     (__attribute__((address_space(3))) unsigned int*)l,
                                     16, 0, 0);
}

// sizes
#define N1 6291456   // x: 4*2048*768
#define N2 1769472   // w_qkv: 2304*768
#define N3 589824    // w_proj: 768*768

// ---------------- Kernel 0: fp32 -> bf16 conversion ----------------
__global__ __launch_bounds__(256) void cvt_bf16(const float* __restrict__ x,
                                                const float* __restrict__ wq,
                                                const float* __restrict__ wp,
                                                u16* __restrict__ xb,
                                                u16* __restrict__ wqb,
                                                u16* __restrict__ wpb) {
    size_t i = ((size_t)blockIdx.x * 256 + threadIdx.x) * 8;
    const float* src;
    u16* dst;
    size_t off;
    if (i < N1)            { src = x;  dst = xb;  off = i; }
    else if (i < N1 + N2)  { src = wq; dst = wqb; off = i - N1; }
    else                   { src = wp; dst = wpb; off = i - N1 - N2; }
    f32x8 v = *(const f32x8*)(src + off);
    short8 o;
#pragma unroll
    for (int j = 0; j < 8; ++j) o[j] = (short)f2bf(v[j]);
    *(short8*)(dst + off) = o;
}

// ---------------- Kernel 1: QKV projection (round-9 verified) ----------------
__global__ __launch_bounds__(256) void qkv_gemm(const u16* __restrict__ X,
                                                const u16* __restrict__ W,
                                                u16* __restrict__ Qb,
                                                u16* __restrict__ Kb,
                                                u16* __restrict__ Vt) {
    __shared__ __align__(16) u16 abuf[128 * 64];
    __shared__ __align__(16) u16 bbuf[128 * 64];

    const int id = blockIdx.x;
    const int swz = (id & 7) * 144 + (id >> 3);   // 1152 = 8 XCD x 144
    const int m0 = (swz & 63) * 128;
    const int n0 = (swz >> 6) * 128;
    const int tid = threadIdx.x;
    const int lane = tid & 63;
    const int w = tid >> 6;
    const int wm = (w >> 1) * 64, wn = (w & 1) * 64;
    const int lrow = lane & 15, rgrp = lane >> 4;

    const int sr = lane >> 3;
    const int schunk = (lane & 7) ^ (sr & 7);
    const u16* asrc = X + (size_t)(m0 + w * 32 + sr) * 768 + schunk * 8;
    const u16* bsrc = W + (size_t)(n0 + w * 32 + sr) * 768 + schunk * 8;
    u16* adst = abuf + (w * 32) * 64;
    u16* bdst = bbuf + (w * 32) * 64;

    f32x4 acc[4][4] = {};

    for (int k0 = 0; k0 < 768; k0 += 64) {
        __syncthreads();
#pragma unroll
        for (int p = 0; p < 4; ++p) {
            gload16(asrc + (size_t)(p * 8) * 768 + k0, adst + (p * 8) * 64);
            gload16(bsrc + (size_t)(p * 8) * 768 + k0, bdst + (p * 8) * 64);
        }
        __syncthreads();

        __builtin_amdgcn_s_setprio(1);
#pragma unroll
        for (int ks = 0; ks < 2; ++ks) {
            short8 a[4], b[4];
            const int cs = (ks * 4 + rgrp);
#pragma unroll
            for (int mf = 0; mf < 4; ++mf)
                a[mf] = *(const short8*)(abuf + (wm + mf * 16 + lrow) * 64 + ((cs ^ (lrow & 7)) * 8));
#pragma unroll
            for (int nf = 0; nf < 4; ++nf)
                b[nf] = *(const short8*)(bbuf + (wn + nf * 16 + lrow) * 64 + ((cs ^ (lrow & 7)) * 8));
#pragma unroll
            for (int mf = 0; mf < 4; ++mf)
#pragma unroll
                for (int nf = 0; nf < 4; ++nf)
                    acc[mf][nf] = MFMA(a[mf], b[nf], acc[mf][nf]);
        }
        __builtin_amdgcn_s_setprio(0);
    }

    const int which = n0 / 768;  // 0=q 1=k 2=v (tiles never straddle)
    if (which < 2) {
        u16* dst = (which == 0) ? Qb : Kb;
        const float scl = (which == 0) ? 0.180336879f : 1.0f;  // 0.125 * log2(e)
#pragma unroll
        for (int mf = 0; mf < 4; ++mf)
#pragma unroll
            for (int nf = 0; nf < 4; ++nf)
#pragma unroll
                for (int r = 0; r < 4; ++r) {
                    int m = m0 + wm + mf * 16 + rgrp * 4 + r;
                    int d = n0 + wn + nf * 16 + lrow - which * 768;
                    int h = d >> 6, e = d & 63;
                    int bb = m >> 11, nseq = m & 2047;
                    dst[(((size_t)bb * 12 + h) * 2048 + nseq) * 64 + e] = f2bf(acc[mf][nf][r] * scl);
                }
    } else {
        // V^T: Vt[((b*12+h)*64 + e)*2048 + nseq]; r=0..3 consecutive nseq
#pragma unroll
        for (int mf = 0; mf < 4; ++mf) {
            const int m = m0 + wm + mf * 16 + rgrp * 4;   // base of the 4-run
            const int bb = m >> 11, nseq = m & 2047;
#pragma unroll
            for (int nf = 0; nf < 4; ++nf) {
                const int d = n0 + wn + nf * 16 + lrow - 1536;
                const int h = d >> 6, e = d & 63;
                u16x4 v4;
#pragma unroll
                for (int r = 0; r < 4; ++r) v4[r] = f2bf(acc[mf][nf][r]);
                *(u16x4*)(Vt + ((((size_t)bb * 12 + h) * 64 + e) * 2048 + nseq)) = v4;
            }
        }
    }
}

// ---------------- Kernel 2: flash attention (single-buffer, 4 blocks/CU) ----
// 768 blocks x 512 threads; 8 waves x 16 q-rows. KVBLK=64, SINGLE-buffered K/V
// (LDS 34KB -> 4 blocks/CU = 32 waves/CU vs dbuf's 3/24): r9-vs-r11 measured
// that cross-block wave overlap at higher occupancy beats intra-block dbuf.
// 2 barriers/kt: {sync(prev compute done) -> stage(kt) -> sync -> compute}.
// Same swizzles / pbuf / swapped-QK^T static-max path as the verified r12.
__global__ __launch_bounds__(512) void attn_kernel(const u16* __restrict__ Qb,
                                                   const u16* __restrict__ Kb,
                                                   const u16* __restrict__ Vt,
                                                   u16* __restrict__ AO) {
    __shared__ __align__(16) u16 kbuf[4096];
    __shared__ __align__(16) u16 vbuf[4096];
    __shared__ __align__(16) u16 pbuf[8][16 * 72];

    const int id = blockIdx.x;
    const int xcd = id & 7, per = id >> 3;        // 96 blocks per XCD = 6 bh
    const int bh = xcd * 6 + (per >> 4);
    const int q0 = (per & 15) * 128;
    const int tid = threadIdx.x;
    const int lane = tid & 63;
    const int w = tid >> 6;
    const int lrow = lane & 15, rgrp = lane >> 4, lk = rgrp * 8;

    const u16* Qp = Qb + (size_t)bh * 2048 * 64;
    const u16* Kp = Kb + (size_t)bh * 2048 * 64;
    const u16* Vp = Vt + (size_t)bh * 64 * 2048;

    const int srow = w * 8 + (lane >> 3);
    const int schunk = lane & 7;
    const int sswz = schunk ^ (srow & 7);
    const u16* ksrc = Kp + srow * 64 + sswz * 8;              // + kt*4096
    const u16* vsrc = Vp + (size_t)srow * 2048 + sswz * 8;    // + kt*64
    const int woff = w * 512;

    const int row0 = q0 + w * 16;
    short8 qf[2];
#pragma unroll
    for (int ks = 0; ks < 2; ++ks)
        qf[ks] = *(const short8*)(Qp + (size_t)(row0 + lrow) * 64 + ks * 32 + lk);

    f32x4 oacc[4] = {};
    float lrun = 0.f;                 // per-lane partial for query lrow
    const f32x4 minit = {-16.f, -16.f, -16.f, -16.f};

    u16* Pw = pbuf[w];
    const int swz = lane & 7;

    for (int kt = 0; kt < 32; ++kt) {
        __syncthreads();              // prev compute done before overwrite
        gload16(ksrc + kt * 4096, kbuf + woff);
        gload16(vsrc + kt * 64,   vbuf + woff);
        __syncthreads();              // vmcnt drained -> tile visible

        // S^T = K Q^T  (swapped: lane holds query=lrow, keys nf*16+rgrp*4+r);
        // C-init of the first k-slice carries the -16 static-max shift.
        f32x4 sacc[4];
        __builtin_amdgcn_s_setprio(1);
#pragma unroll
        for (int nf = 0; nf < 4; ++nf) {
            short8 kf0 = *(const short8*)(kbuf + (nf * 16 + lrow) * 64 + ((rgrp ^ swz) * 8));
            sacc[nf] = MFMA(kf0, qf[0], minit);
            short8 kf1 = *(const short8*)(kbuf + (nf * 16 + lrow) * 64 + (((4 + rgrp) ^ swz) * 8));
            sacc[nf] = MFMA(kf1, qf[1], sacc[nf]);
        }
        __builtin_amdgcn_s_setprio(0);

        // P = exp2(S - 16); pack r-quads -> ds_write_b64; accumulate l partial
#pragma unroll
        for (int nf = 0; nf < 4; ++nf) {
            float p0 = exp2fast(sacc[nf][0]);
            float p1 = exp2fast(sacc[nf][1]);
            float p2 = exp2fast(sacc[nf][2]);
            float p3 = exp2fast(sacc[nf][3]);
            lrun += (p0 + p1) + (p2 + p3);
            u32x2 pk;
            pk.x = cvtpk(p0, p1);
            pk.y = cvtpk(p2, p3);
            *(u32x2*)&Pw[lrow * 72 + nf * 16 + rgrp * 4] = pk;
        }

        // O += P V
        __builtin_amdgcn_s_setprio(1);
#pragma unroll
        for (int ks = 0; ks < 2; ++ks) {
            short8 pa = *(const short8*)&Pw[lrow * 72 + ks * 32 + lk];
#pragma unroll
            for (int df = 0; df < 4; ++df) {
                short8 vf = *(const short8*)(vbuf + (df * 16 + lrow) * 64 + ((ks * 4 + rgrp) ^ swz) * 8);
                oacc[df] = MFMA(pa, vf, oacc[df]);
            }
        }
        __builtin_amdgcn_s_setprio(0);
    }

    // epilogue: reduce l partials (query lrow lives on lanes lrow+{0,16,32,48})
    float l = lrun;
    l += __shfl_xor(l, 16);
    l += __shfl_xor(l, 32);
    float linv[4];
#pragma unroll
    for (int r = 0; r < 4; ++r) linv[r] = 1.f / __shfl(l, rgrp * 4 + r);

    const int b = bh / 12, h = bh % 12;
#pragma unroll
    for (int r = 0; r < 4; ++r) {
        int row = row0 + rgrp * 4 + r;
#pragma unroll
        for (int df = 0; df < 4; ++df)
            AO[((size_t)b * 2048 + row) * 768 + h * 64 + df * 16 + lrow] = f2bf(oacc[df][r] * linv[r]);
    }
}

// ---------------- Kernel 3: output projection (round-9 verified) -------------
__global__ __launch_bounds__(256) void proj_gemm(const u16* __restrict__ A,
                                                 const u16* __restrict__ W,
                                                 const float* __restrict__ bias,
                                                 float* __restrict__ out) {
    __shared__ __align__(16) u16 abuf[64 * 64];    // 8KB
    __shared__ __align__(16) u16 bbuf[128 * 64];   // 16KB

    const int id = blockIdx.x;
    const int swz = (id & 7) * 96 + (id >> 3);     // 768 = 8 XCD x 96
    const int m0 = (swz & 127) * 64;
    const int n0 = (swz >> 7) * 128;
    const int tid = threadIdx.x;
    const int lane = tid & 63;
    const int w = tid >> 6;
    const int lrow = lane & 15, rgrp = lane >> 4;

    const int sra = w * 16 + (lane >> 3);
    const int srb = w * 32 + (lane >> 3);
    const int aswz = (lane & 7) ^ (sra & 7);
    const int bswz = (lane & 7) ^ (srb & 7);
    const u16* asrc = A + (size_t)(m0 + sra) * 768 + aswz * 8;
    const u16* bsrc = W + (size_t)(n0 + srb) * 768 + bswz * 8;
    u16* adst0 = abuf + (w * 16) * 64;
    u16* bdst0 = bbuf + (w * 32) * 64;

    f32x4 acc[4][2] = {};

    for (int k0 = 0; k0 < 768; k0 += 64) {
        __syncthreads();
#pragma unroll
        for (int p = 0; p < 2; ++p)
            gload16(asrc + (size_t)(p * 8) * 768 + k0, adst0 + (p * 8) * 64);
#pragma unroll
        for (int p = 0; p < 4; ++p)
            gload16(bsrc + (size_t)(p * 8) * 768 + k0, bdst0 + (p * 8) * 64);
        __syncthreads();

        __builtin_amdgcn_s_setprio(1);
#pragma unroll
        for (int ks = 0; ks < 2; ++ks) {
            short8 a[4], b[2];
            const int cs = (ks * 4 + rgrp);
#pragma unroll
            for (int mf = 0; mf < 4; ++mf)
                a[mf] = *(const short8*)(abuf + (mf * 16 + lrow) * 64 + ((cs ^ (lrow & 7)) * 8));
#pragma unroll
            for (int nf = 0; nf < 2; ++nf)
                b[nf] = *(const short8*)(bbuf + (w * 32 + nf * 16 + lrow) * 64 + ((cs ^ (lrow & 7)) * 8));
#pragma unroll
            for (int mf = 0; mf < 4; ++mf)
#pragma unroll
                for (int nf = 0; nf < 2; ++nf)
                    acc[mf][nf] = MFMA(a[mf], b[nf], acc[mf][nf]);
        }
        __builtin_amdgcn_s_setprio(0);
    }

#pragma unroll
    for (int nf = 0; nf < 2; ++nf) {
        const int d = n0 + w * 32 + nf * 16 + lrow;
        const float bv = bias[d];
#pragma unroll
        for (int mf = 0; mf < 4; ++mf)
#pragma unroll
            for (int r = 0; r < 4; ++r) {
                const int m = m0 + mf * 16 + rgrp * 4 + r;
                out[(size_t)m * 768 + d] = acc[mf][nf][r] + bv;
            }
    }
}

extern "C" void kernel_launch(void* const* d_in, const int* in_sizes, int n_in,
                              void* d_out, int out_size, void* d_ws, size_t ws_size,
                              hipStream_t stream) {
    const float* x      = (const float*)d_in[0];
    const float* w_qkv  = (const float*)d_in[1];
    const float* w_proj = (const float*)d_in[2];
    const float* b_proj = (const float*)d_in[3];
    float* out = (float*)d_out;

    const size_t per = (size_t)48 * 2048 * 64;  // 6,291,456
    u16* Qb  = (u16*)d_ws;
    u16* Kb  = Qb + per;
    u16* Vt  = Kb + per;
    u16* XB  = Vt + per;        // bf16 x; ALIASES AO (x dead after qkv_gemm)
    u16* AO  = XB;
    u16* WQB = XB + per;
    u16* WPB = WQB + (size_t)N2;

    cvt_bf16<<<4224, 256, 0, stream>>>(x, w_qkv, w_proj, XB, WQB, WPB);
    qkv_gemm<<<1152, 256, 0, stream>>>(XB, WQB, Qb, Kb, Vt);
    attn_kernel<<<768, 512, 0, stream>>>(Qb, Kb, Vt, AO);
    proj_gemm<<<768, 256, 0, stream>>>(AO, WPB, b_proj, out);
}

// Round 14
// 145.057 us; speedup vs baseline: 1.0308x; 1.0308x over previous
//
#include <hip/hip_runtime.h>

typedef unsigned short u16;
typedef unsigned int u32;
typedef __attribute__((ext_vector_type(4))) unsigned short u16x4;
typedef __attribute__((ext_vector_type(8))) short short8;
typedef __attribute__((ext_vector_type(4))) float f32x4;
typedef __attribute__((ext_vector_type(8))) float f32x8;
typedef __attribute__((ext_vector_type(2))) unsigned int u32x2;

#define MFMA(a, b, c) __builtin_amdgcn_mfma_f32_16x16x32_bf16((a), (b), (c), 0, 0, 0)

__device__ __forceinline__ u16 f2bf(float f) {
    union { float f; unsigned int u; } v; v.f = f;
    unsigned int u = v.u;
    return (u16)((u + 0x7fffu + ((u >> 16) & 1u)) >> 16);
}

__device__ __forceinline__ float exp2fast(float x) {
#if __has_builtin(__builtin_amdgcn_exp2f)
    return __builtin_amdgcn_exp2f(x);
#else
    return exp2f(x);
#endif
}

__device__ __forceinline__ unsigned int cvtpk(float lo, float hi) {
    unsigned int r;
    asm("v_cvt_pk_bf16_f32 %0, %1, %2" : "=v"(r) : "v"(lo), "v"(hi));
    return r;
}

// async global->LDS, 16B per lane; LDS dest = wave-uniform base + lane*16
__device__ __forceinline__ void gload16(const void* g, void* l) {
    __builtin_amdgcn_global_load_lds((const __attribute__((address_space(1))) unsigned int*)g,
                                     (__attribute__((address_space(3))) unsigned int*)l,
                                     16, 0, 0);
}

// sizes
#define N1 6291456   // x: 4*2048*768
#define N2 1769472   // w_qkv: 2304*768
#define N3 589824    // w_proj: 768*768

// ---------------- Kernel 0: fp32 -> bf16 conversion (HBM-bound, ~8us) -------
__global__ __launch_bounds__(256) void cvt_bf16(const float* __restrict__ x,
                                                const float* __restrict__ wq,
                                                const float* __restrict__ wp,
                                                u16* __restrict__ xb,
                                                u16* __restrict__ wqb,
                                                u16* __restrict__ wpb) {
    size_t i = ((size_t)blockIdx.x * 256 + threadIdx.x) * 8;
    const float* src;
    u16* dst;
    size_t off;
    if (i < N1)            { src = x;  dst = xb;  off = i; }
    else if (i < N1 + N2)  { src = wq; dst = wqb; off = i - N1; }
    else                   { src = wp; dst = wpb; off = i - N1 - N2; }
    f32x8 v = *(const f32x8*)(src + off);
    short8 o;
#pragma unroll
    for (int j = 0; j < 8; ++j) o[j] = (short)f2bf(v[j]);
    *(short8*)(dst + off) = o;
}

// ---------------- Kernel 1: QKV projection -----------------------------------
// 128x128/BK=64 single-buffer (beat BK=32 dbuf and BK=64 dbuf: 146.5 vs 159.7
// vs 150.6 total). Q scaled 0.125*log2(e); V^T ushort4 epilogue.
__global__ __launch_bounds__(256) void qkv_gemm(const u16* __restrict__ X,
                                                const u16* __restrict__ W,
                                                u16* __restrict__ Qb,
                                                u16* __restrict__ Kb,
                                                u16* __restrict__ Vt) {
    __shared__ __align__(16) u16 abuf[128 * 64];
    __shared__ __align__(16) u16 bbuf[128 * 64];

    const int id = blockIdx.x;
    const int swz = (id & 7) * 144 + (id >> 3);   // 1152 = 8 XCD x 144
    const int m0 = (swz & 63) * 128;
    const int n0 = (swz >> 6) * 128;
    const int tid = threadIdx.x;
    const int lane = tid & 63;
    const int w = tid >> 6;
    const int wm = (w >> 1) * 64, wn = (w & 1) * 64;
    const int lrow = lane & 15, rgrp = lane >> 4;

    const int sr = lane >> 3;
    const int schunk = (lane & 7) ^ (sr & 7);
    const u16* asrc = X + (size_t)(m0 + w * 32 + sr) * 768 + schunk * 8;
    const u16* bsrc = W + (size_t)(n0 + w * 32 + sr) * 768 + schunk * 8;
    u16* adst = abuf + (w * 32) * 64;
    u16* bdst = bbuf + (w * 32) * 64;

    f32x4 acc[4][4] = {};

    for (int k0 = 0; k0 < 768; k0 += 64) {
        __syncthreads();
#pragma unroll
        for (int p = 0; p < 4; ++p) {
            gload16(asrc + (size_t)(p * 8) * 768 + k0, adst + (p * 8) * 64);
            gload16(bsrc + (size_t)(p * 8) * 768 + k0, bdst + (p * 8) * 64);
        }
        __syncthreads();

        __builtin_amdgcn_s_setprio(1);
#pragma unroll
        for (int ks = 0; ks < 2; ++ks) {
            short8 a[4], b[4];
            const int cs = (ks * 4 + rgrp);
#pragma unroll
            for (int mf = 0; mf < 4; ++mf)
                a[mf] = *(const short8*)(abuf + (wm + mf * 16 + lrow) * 64 + ((cs ^ (lrow & 7)) * 8));
#pragma unroll
            for (int nf = 0; nf < 4; ++nf)
                b[nf] = *(const short8*)(bbuf + (wn + nf * 16 + lrow) * 64 + ((cs ^ (lrow & 7)) * 8));
#pragma unroll
            for (int mf = 0; mf < 4; ++mf)
#pragma unroll
                for (int nf = 0; nf < 4; ++nf)
                    acc[mf][nf] = MFMA(a[mf], b[nf], acc[mf][nf]);
        }
        __builtin_amdgcn_s_setprio(0);
    }

    const int which = n0 / 768;  // 0=q 1=k 2=v (tiles never straddle)
    if (which < 2) {
        u16* dst = (which == 0) ? Qb : Kb;
        const float scl = (which == 0) ? 0.180336879f : 1.0f;  // 0.125 * log2(e)
#pragma unroll
        for (int mf = 0; mf < 4; ++mf)
#pragma unroll
            for (int nf = 0; nf < 4; ++nf)
#pragma unroll
                for (int r = 0; r < 4; ++r) {
                    int m = m0 + wm + mf * 16 + rgrp * 4 + r;
                    int d = n0 + wn + nf * 16 + lrow - which * 768;
                    int h = d >> 6, e = d & 63;
                    int bb = m >> 11, nseq = m & 2047;
                    dst[(((size_t)bb * 12 + h) * 2048 + nseq) * 64 + e] = f2bf(acc[mf][nf][r] * scl);
                }
    } else {
        // V^T: Vt[((b*12+h)*64 + e)*2048 + nseq]; r=0..3 consecutive nseq
#pragma unroll
        for (int mf = 0; mf < 4; ++mf) {
            const int m = m0 + wm + mf * 16 + rgrp * 4;   // base of the 4-run
            const int bb = m >> 11, nseq = m & 2047;
#pragma unroll
            for (int nf = 0; nf < 4; ++nf) {
                const int d = n0 + wn + nf * 16 + lrow - 1536;
                const int h = d >> 6, e = d & 63;
                u16x4 v4;
#pragma unroll
                for (int r = 0; r < 4; ++r) v4[r] = f2bf(acc[mf][nf][r]);
                *(u16x4*)(Vt + ((((size_t)bb * 12 + h) * 64 + e) * 2048 + nseq)) = v4;
            }
        }
    }
}

// ---------------- Kernel 2: flash attention (single-buffer; LDS-BW-bound) ---
// 768 blocks x 512 threads; 8 waves x 16 q-rows; KVBLK=64. Measured 69.8us ~=
// the 144KB/kt-block / 85B-cyc-CU ds_read_b128 bound (within 2%). Swapped QK^T
// (S^T) + static-max (-16 in MFMA C-init); P via cvt_pk -> ds_write_b64.
__global__ __launch_bounds__(512) void attn_kernel(const u16* __restrict__ Qb,
                                                   const u16* __restrict__ Kb,
                                                   const u16* __restrict__ Vt,
                                                   u16* __restrict__ AO) {
    __shared__ __align__(16) u16 kbuf[4096];
    __shared__ __align__(16) u16 vbuf[4096];
    __shared__ __align__(16) u16 pbuf[8][16 * 72];

    const int id = blockIdx.x;
    const int xcd = id & 7, per = id >> 3;        // 96 blocks per XCD = 6 bh
    const int bh = xcd * 6 + (per >> 4);
    const int q0 = (per & 15) * 128;
    const int tid = threadIdx.x;
    const int lane = tid & 63;
    const int w = tid >> 6;
    const int lrow = lane & 15, rgrp = lane >> 4, lk = rgrp * 8;

    const u16* Qp = Qb + (size_t)bh * 2048 * 64;
    const u16* Kp = Kb + (size_t)bh * 2048 * 64;
    const u16* Vp = Vt + (size_t)bh * 64 * 2048;

    const int srow = w * 8 + (lane >> 3);
    const int schunk = lane & 7;
    const int sswz = schunk ^ (srow & 7);
    const u16* ksrc = Kp + srow * 64 + sswz * 8;              // + kt*4096
    const u16* vsrc = Vp + (size_t)srow * 2048 + sswz * 8;    // + kt*64
    const int woff = w * 512;

    const int row0 = q0 + w * 16;
    short8 qf[2];
#pragma unroll
    for (int ks = 0; ks < 2; ++ks)
        qf[ks] = *(const short8*)(Qp + (size_t)(row0 + lrow) * 64 + ks * 32 + lk);

    f32x4 oacc[4] = {};
    float lrun = 0.f;                 // per-lane partial for query lrow
    const f32x4 minit = {-16.f, -16.f, -16.f, -16.f};

    u16* Pw = pbuf[w];
    const int swz = lane & 7;

    for (int kt = 0; kt < 32; ++kt) {
        __syncthreads();              // prev compute done before overwrite
        gload16(ksrc + kt * 4096, kbuf + woff);
        gload16(vsrc + kt * 64,   vbuf + woff);
        __syncthreads();              // vmcnt drained -> tile visible

        // S^T = K Q^T  (swapped: lane holds query=lrow, keys nf*16+rgrp*4+r);
        // C-init of the first k-slice carries the -16 static-max shift.
        f32x4 sacc[4];
        __builtin_amdgcn_s_setprio(1);
#pragma unroll
        for (int nf = 0; nf < 4; ++nf) {
            short8 kf0 = *(const short8*)(kbuf + (nf * 16 + lrow) * 64 + ((rgrp ^ swz) * 8));
            sacc[nf] = MFMA(kf0, qf[0], minit);
            short8 kf1 = *(const short8*)(kbuf + (nf * 16 + lrow) * 64 + (((4 + rgrp) ^ swz) * 8));
            sacc[nf] = MFMA(kf1, qf[1], sacc[nf]);
        }
        __builtin_amdgcn_s_setprio(0);

        // P = exp2(S - 16); pack r-quads -> ds_write_b64; accumulate l partial
#pragma unroll
        for (int nf = 0; nf < 4; ++nf) {
            float p0 = exp2fast(sacc[nf][0]);
            float p1 = exp2fast(sacc[nf][1]);
            float p2 = exp2fast(sacc[nf][2]);
            float p3 = exp2fast(sacc[nf][3]);
            lrun += (p0 + p1) + (p2 + p3);
            u32x2 pk;
            pk.x = cvtpk(p0, p1);
            pk.y = cvtpk(p2, p3);
            *(u32x2*)&Pw[lrow * 72 + nf * 16 + rgrp * 4] = pk;
        }

        // O += P V
        __builtin_amdgcn_s_setprio(1);
#pragma unroll
        for (int ks = 0; ks < 2; ++ks) {
            short8 pa = *(const short8*)&Pw[lrow * 72 + ks * 32 + lk];
#pragma unroll
            for (int df = 0; df < 4; ++df) {
                short8 vf = *(const short8*)(vbuf + (df * 16 + lrow) * 64 + ((ks * 4 + rgrp) ^ swz) * 8);
                oacc[df] = MFMA(pa, vf, oacc[df]);
            }
        }
        __builtin_amdgcn_s_setprio(0);
    }

    // epilogue: reduce l partials (query lrow lives on lanes lrow+{0,16,32,48})
    float l = lrun;
    l += __shfl_xor(l, 16);
    l += __shfl_xor(l, 32);
    float linv[4];
#pragma unroll
    for (int r = 0; r < 4; ++r) linv[r] = 1.f / __shfl(l, rgrp * 4 + r);

    const int b = bh / 12, h = bh % 12;
#pragma unroll
    for (int r = 0; r < 4; ++r) {
        int row = row0 + rgrp * 4 + r;
#pragma unroll
        for (int df = 0; df < 4; ++df)
            AO[((size_t)b * 2048 + row) * 768 + h * 64 + df * 16 + lrow] = f2bf(oacc[df][r] * linv[r]);
    }
}

// ---------------- Kernel 3: output projection (BM=64, BN=128, 768 blocks) ---
__global__ __launch_bounds__(256) void proj_gemm(const u16* __restrict__ A,
                                                 const u16* __restrict__ W,
                                                 const float* __restrict__ bias,
                                                 float* __restrict__ out) {
    __shared__ __align__(16) u16 abuf[64 * 64];    // 8KB
    __shared__ __align__(16) u16 bbuf[128 * 64];   // 16KB

    const int id = blockIdx.x;
    const int swz = (id & 7) * 96 + (id >> 3);     // 768 = 8 XCD x 96
    const int m0 = (swz & 127) * 64;
    const int n0 = (swz >> 7) * 128;
    const int tid = threadIdx.x;
    const int lane = tid & 63;
    const int w = tid >> 6;
    const int lrow = lane & 15, rgrp = lane >> 4;

    const int sra = w * 16 + (lane >> 3);
    const int srb = w * 32 + (lane >> 3);
    const int aswz = (lane & 7) ^ (sra & 7);
    const int bswz = (lane & 7) ^ (srb & 7);
    const u16* asrc = A + (size_t)(m0 + sra) * 768 + aswz * 8;
    const u16* bsrc = W + (size_t)(n0 + srb) * 768 + bswz * 8;
    u16* adst0 = abuf + (w * 16) * 64;
    u16* bdst0 = bbuf + (w * 32) * 64;

    f32x4 acc[4][2] = {};

    for (int k0 = 0; k0 < 768; k0 += 64) {
        __syncthreads();
#pragma unroll
        for (int p = 0; p < 2; ++p)
            gload16(asrc + (size_t)(p * 8) * 768 + k0, adst0 + (p * 8) * 64);
#pragma unroll
        for (int p = 0; p < 4; ++p)
            gload16(bsrc + (size_t)(p * 8) * 768 + k0, bdst0 + (p * 8) * 64);
        __syncthreads();

        __builtin_amdgcn_s_setprio(1);
#pragma unroll
        for (int ks = 0; ks < 2; ++ks) {
            short8 a[4], b[2];
            const int cs = (ks * 4 + rgrp);
#pragma unroll
            for (int mf = 0; mf < 4; ++mf)
                a[mf] = *(const short8*)(abuf + (mf * 16 + lrow) * 64 + ((cs ^ (lrow & 7)) * 8));
#pragma unroll
            for (int nf = 0; nf < 2; ++nf)
                b[nf] = *(const short8*)(bbuf + (w * 32 + nf * 16 + lrow) * 64 + ((cs ^ (lrow & 7)) * 8));
#pragma unroll
            for (int mf = 0; mf < 4; ++mf)
#pragma unroll
                for (int nf = 0; nf < 2; ++nf)
                    acc[mf][nf] = MFMA(a[mf], b[nf], acc[mf][nf]);
        }
        __builtin_amdgcn_s_setprio(0);
    }

#pragma unroll
    for (int nf = 0; nf < 2; ++nf) {
        const int d = n0 + w * 32 + nf * 16 + lrow;
        const float bv = bias[d];
#pragma unroll
        for (int mf = 0; mf < 4; ++mf)
#pragma unroll
            for (int r = 0; r < 4; ++r) {
                const int m = m0 + mf * 16 + rgrp * 4 + r;
                out[(size_t)m * 768 + d] = acc[mf][nf][r] + bv;
            }
    }
}

extern "C" void kernel_launch(void* const* d_in, const int* in_sizes, int n_in,
                              void* d_out, int out_size, void* d_ws, size_t ws_size,
                              hipStream_t stream) {
    const float* x      = (const float*)d_in[0];
    const float* w_qkv  = (const float*)d_in[1];
    const float* w_proj = (const float*)d_in[2];
    const float* b_proj = (const float*)d_in[3];
    float* out = (float*)d_out;

    const size_t per = (size_t)48 * 2048 * 64;  // 6,291,456
    u16* Qb  = (u16*)d_ws;
    u16* Kb  = Qb + per;
    u16* Vt  = Kb + per;
    u16* XB  = Vt + per;        // bf16 x; ALIASES AO (x dead after qkv_gemm)
    u16* AO  = XB;
    u16* WQB = XB + per;
    u16* WPB = WQB + (size_t)N2;

    cvt_bf16<<<4224, 256, 0, stream>>>(x, w_qkv, w_proj, XB, WQB, WPB);
    qkv_gemm<<<1152, 256, 0, stream>>>(XB, WQB, Qb, Kb, Vt);
    attn_kernel<<<768, 512, 0, stream>>>(Qb, Kb, Vt, AO);
    proj_gemm<<<768, 256, 0, stream>>>(AO, WPB, b_proj, out);
}